// Round 6
// baseline (7817.003 us; speedup 1.0000x reference)
//
#include <hip/hip_runtime.h>
#include <hip/hip_bf16.h>

// LatticeLSTM on MI355X — Round 6: dual-path (L2-fast / MALL-correct)
// publication + poll prefetch + critical-tail motion.
//  - Every cross-WG datum is ONE 8B word {fp32 val, u32 gen}. Producer
//    publishes TWICE: volatile plain store (lands in producer-XCD L2; fast
//    path when consumer shares the XCD — grid (seq, wg) round-robin
//    heuristic) then agent-scope atomic store (correct under ANY mapping).
//    Consumers poll volatile (fast) with an agent-scope atomic fallback every
//    8th iteration (guaranteed progress). Gen-tagged words make stale reads
//    retries, never corruption; single producer per address -> monotone gens.
//  - Pend loads for step t issued BEFORE A1 (latency hides under compute).
//  - h-independent reductions moved pre-S1; x-dependent word matvecs +
//    reductions moved pre-h-poll: post-S2 tail = 3 matvecs + 3 red16 + gates.
// pmask is data-independent: m0=(t>=1), m1=(t>=3); c_plain only at t=0.
// Progress needs all 256 WGs co-resident (1 WG/CU; LDS ~11KB, VGPR<256).

#define Bq 8
#define Tq 1024
#define DCq 128
#define Hq 512
#define NWG 32
#define NTHR 256

typedef unsigned long long u64;

// ws byte offsets
#define HPUB_OFF  0u         // u64 h_pub[8][2][512]     = 65536
#define PENDP_OFF 65536u     // u64 pend[8][4][2][512]   = 262144
#define WIHT_OFF  327680u    // bf16 [1536][128]
#define WHHT_OFF  720896u    // bf16 [1536][512]
#define AWIHT_OFF 2293760u   // bf16 [512][128]
#define AWHHT_OFF 2424832u   // bf16 [512][512]
#define WWIHT_OFF 2949120u   // bf16 [1536][128]
#define WWHHT_OFF 3342336u   // bf16 [1536][512]  (end 4915200)

__device__ __forceinline__ float bflo(unsigned u){ return __uint_as_float(u << 16); }
__device__ __forceinline__ float bfhi(unsigned u){ return __uint_as_float(u & 0xffff0000u); }
__device__ __forceinline__ float sigm(float x){ return 1.0f / (1.0f + __expf(-x)); }

__device__ __forceinline__ void fma4(float& acc, uint2 w, float4 v){
  acc = fmaf(bflo(w.x), v.x, acc);
  acc = fmaf(bfhi(w.x), v.y, acc);
  acc = fmaf(bflo(w.y), v.z, acc);
  acc = fmaf(bfhi(w.y), v.w, acc);
}

__device__ __forceinline__ float red16(float x){
  x += __shfl_xor(x, 8, 16);
  x += __shfl_xor(x, 4, 16);
  x += __shfl_xor(x, 2, 16);
  x += __shfl_xor(x, 1, 16);
  return x;
}

__device__ __forceinline__ u64 pack64(float v, unsigned gen){
  return ((u64)gen << 32) | (u64)__float_as_uint(v);
}
// dual-path publish: volatile (local-XCD L2, fast) then agent atomic (correct)
__device__ __forceinline__ void pub64(u64* p, float v, unsigned gen){
  u64 w = pack64(v, gen);
  *(volatile u64*)p = w;
  __hip_atomic_store(p, w, __ATOMIC_RELAXED, __HIP_MEMORY_SCOPE_AGENT);
}
__device__ __forceinline__ u64 ld64(const u64* p){
  return __hip_atomic_load(p, __ATOMIC_RELAXED, __HIP_MEMORY_SCOPE_AGENT);
}
__device__ __forceinline__ u64 vld64(const u64* p){
  return *(volatile const u64*)p;
}
__device__ __forceinline__ unsigned genof(u64 v){ return (unsigned)(v >> 32); }
__device__ __forceinline__ float valof(u64 v){ return __uint_as_float((unsigned)v); }

// src [K][N] fp32 -> dst [N][K] bf16 (transpose + convert). K is pow2.
__global__ void transpose_bf16(const float* __restrict__ src, __hip_bfloat16* __restrict__ dst,
                               int kshift, int total, int N){
  const int K = 1 << kshift;
  for (int idx = blockIdx.x * blockDim.x + threadIdx.x; idx < total;
       idx += gridDim.x * blockDim.x){
    int n = idx >> kshift;
    int k = idx & (K - 1);
    dst[idx] = __float2bfloat16(src[(size_t)k * N + n]);
  }
}

__global__ void __launch_bounds__(NTHR, 1)
lattice_main(const float* __restrict__ char_emb,
             const int*   __restrict__ word_ids,
             const float* __restrict__ sense_table,
             const float* __restrict__ bias_b,
             const float* __restrict__ bias_ab,
             const float* __restrict__ bias_wb,
             unsigned char* __restrict__ ws,
             float* __restrict__ out)
{
  const int seq  = blockIdx.x;
  const int wg   = blockIdx.y;
  const int tid  = threadIdx.x;
  const int grp  = tid >> 4;
  const int lane = tid & 15;
  const int J    = wg * 16 + grp;               // owned H column
  const int i0   = tid * 2, i1 = tid * 2 + 1;   // poll columns for this thread

  u64* hpub = (u64*)(ws + HPUB_OFF)  + (size_t)seq * 2 * Hq;      // [parity][col]
  u64* pnd  = (u64*)(ws + PENDP_OFF) + (size_t)seq * 4 * 2 * Hq;  // [slot][k][col]

  const uint2* w_ihT  = (const uint2*)(ws + WIHT_OFF);
  const uint2* w_hhT  = (const uint2*)(ws + WHHT_OFF);
  const uint2* aw_ihT = (const uint2*)(ws + AWIHT_OFF);
  const uint2* aw_hhT = (const uint2*)(ws + AWHHT_OFF);
  const uint2* ww_ihT = (const uint2*)(ws + WWIHT_OFF);
  const uint2* ww_hhT = (const uint2*)(ws + WWHHT_OFF);

  // ---- hoist ALL weights into registers (addresses are t-invariant) ----
  uint2 Rwhh_i[8], Rwhh_o[8], Rwhh_g[8], Rawhh[8];
  uint2 Rwwh_f[8], Rwwh_i[8], Rwwh_g[8];
  uint2 Rwih_i[2], Rwih_o[2], Rwih_g[2], Rawih[2];
  uint2 Rwwi_f[2], Rwwi_i[2], Rwwi_g[2];
  {
    const uint2* whh_i = w_hhT  + (size_t)(0*Hq + J) * 128;
    const uint2* whh_o = w_hhT  + (size_t)(1*Hq + J) * 128;
    const uint2* whh_g = w_hhT  + (size_t)(2*Hq + J) * 128;
    const uint2* awhh  = aw_hhT + (size_t)J * 128;
    const uint2* wwh_f = ww_hhT + (size_t)(0*Hq + J) * 128;
    const uint2* wwh_i = ww_hhT + (size_t)(1*Hq + J) * 128;
    const uint2* wwh_g = ww_hhT + (size_t)(2*Hq + J) * 128;
#pragma unroll
    for (int it = 0; it < 8; ++it){
      const int q = it * 16 + lane;
      Rwhh_i[it] = whh_i[q];  Rwhh_o[it] = whh_o[q];  Rwhh_g[it] = whh_g[q];
      Rawhh[it]  = awhh[q];
      Rwwh_f[it] = wwh_f[q];  Rwwh_i[it] = wwh_i[q];  Rwwh_g[it] = wwh_g[q];
    }
    const uint2* wih_i = w_ihT  + (size_t)(0*Hq + J) * 32;
    const uint2* wih_o = w_ihT  + (size_t)(1*Hq + J) * 32;
    const uint2* wih_g = w_ihT  + (size_t)(2*Hq + J) * 32;
    const uint2* awih  = aw_ihT + (size_t)J * 32;
    const uint2* wwi_f = ww_ihT + (size_t)(0*Hq + J) * 32;
    const uint2* wwi_i = ww_ihT + (size_t)(1*Hq + J) * 32;
    const uint2* wwi_g = ww_ihT + (size_t)(2*Hq + J) * 32;
#pragma unroll
    for (int it = 0; it < 2; ++it){
      const int q = it * 16 + lane;
      Rwih_i[it] = wih_i[q];  Rwih_o[it] = wih_o[q];  Rwih_g[it] = wih_g[q];
      Rawih[it]  = awih[q];
      Rwwi_f[it] = wwi_f[q];  Rwwi_i[it] = wwi_i[q];  Rwwi_g[it] = wwi_g[q];
    }
  }

  const float b_i  = bias_b[J], b_o = bias_b[Hq + J], b_g = bias_b[2*Hq + J];
  const float ab_J = bias_ab[J];
  const float wb_f = bias_wb[J], wb_i = bias_wb[Hq + J], wb_g = bias_wb[2*Hq + J];

  float* out_h = out + (size_t)seq * Tq * Hq;            // hs block
  float* out_c = out + ((size_t)Bq + seq) * Tq * Hq;     // cs block

  __shared__ __align__(16) float shH[2][Hq];      // h by parity: shH[t&1] = h(t)
  __shared__ __align__(16) float sh_p0[Hq];
  __shared__ __align__(16) float sh_p1[Hq];
  __shared__ __align__(16) float shx[2][DCq];     // x(t) in shx[t&1]
  __shared__ __align__(16) float shxw0[2][DCq];   // xw(t) in shxw*[t&1]
  __shared__ __align__(16) float shxw1[2][DCq];

  // ---- pre-loop staging: zeros + x(0), xw(0) ----
  shH[0][i0] = 0.f; shH[0][i1] = 0.f;
  shH[1][i0] = 0.f; shH[1][i1] = 0.f;
  sh_p0[i0] = 0.f; sh_p0[i1] = 0.f;
  sh_p1[i0] = 0.f; sh_p1[i1] = 0.f;
  if (tid < DCq){
    shx[0][tid] = char_emb[((size_t)seq * Tq + 0) * DCq + tid];
  } else {
    const int k = tid - DCq;
    const int w0 = word_ids[(size_t)seq * Tq * 2 + 0];
    const int w1 = word_ids[(size_t)seq * Tq * 2 + 1];
    shxw0[0][k] = sense_table[(size_t)w0 * DCq + k];
    shxw1[0][k] = sense_table[(size_t)w1 * DCq + k];
  }
  __syncthreads();

  for (int t = 0; t < Tq; ++t){
    const int par = t & 1;
    const float* hprev = shH[par ^ 1];     // h(t-1)

    // ---- pend PREFETCH (issued before A1; latency hides under compute) ----
    const u64* p0 = pnd + ((size_t)(t & 3) * 2 + 0) * Hq;
    const u64* p1 = pnd + ((size_t)(t & 3) * 2 + 1) * Hq;
    u64 qa = 0, qb = 0, qc = 0, qd = 0;
    if (t >= 1){ qa = vld64(p0 + i0); qb = vld64(p0 + i1); }
    if (t >= 3){ qc = vld64(p1 + i0); qd = vld64(p1 + i1); }

    // ---- A1: i/o/g/xa matvecs (pend NOT needed) ----
    float a_i = 0.f, a_o = 0.f, a_g = 0.f, a_xa = 0.f;
#pragma unroll
    for (int it = 0; it < 8; ++it){
      const int k0 = it * 64 + lane * 4;
      float4 hv = *(const float4*)(hprev + k0);
      fma4(a_i, Rwhh_i[it], hv);
      fma4(a_o, Rwhh_o[it], hv);
      fma4(a_g, Rwhh_g[it], hv);
    }
#pragma unroll
    for (int it = 0; it < 2; ++it){
      const int k0 = it * 64 + lane * 4;
      float4 xv = *(const float4*)(shx[par] + k0);
      fma4(a_i,  Rwih_i[it], xv);
      fma4(a_o,  Rwih_o[it], xv);
      fma4(a_g,  Rwih_g[it], xv);
      fma4(a_xa, Rawih[it],  xv);
    }
    // h-independent reductions BEFORE S1 (execute under any poll wait)
    a_i  = red16(a_i);  a_o  = red16(a_o);  a_g  = red16(a_g);  a_xa = red16(a_xa);

    // ---- A2: check prefetched pend; re-poll volatile w/ atomic fallback ----
    if (t >= 3){
      const unsigned tg0 = (unsigned)t, tg1 = (unsigned)(t - 2);
      int itc = 0;
      while (!(genof(qa) >= tg0 && genof(qb) >= tg0 &&
               genof(qc) >= tg1 && genof(qd) >= tg1)){
        if ((++itc & 7) == 0){
          qa = ld64(p0 + i0);  qb = ld64(p0 + i1);
          qc = ld64(p1 + i0);  qd = ld64(p1 + i1);
        } else {
          qa = vld64(p0 + i0); qb = vld64(p0 + i1);
          qc = vld64(p1 + i0); qd = vld64(p1 + i1);
        }
      }
      sh_p0[i0] = valof(qa); sh_p0[i1] = valof(qb);
      sh_p1[i0] = valof(qc); sh_p1[i1] = valof(qd);
    } else if (t >= 1){
      const unsigned tg0 = (unsigned)t;
      int itc = 0;
      while (!(genof(qa) >= tg0 && genof(qb) >= tg0)){
        if ((++itc & 7) == 0){
          qa = ld64(p0 + i0);  qb = ld64(p0 + i1);
        } else {
          qa = vld64(p0 + i0); qb = vld64(p0 + i1);
        }
      }
      sh_p0[i0] = valof(qa); sh_p0[i1] = valof(qb);
      // sh_p1 stays zero (m1=0 for t<3)
    }
    __syncthreads();   // S1

    // ---- A3: alpha matvecs + gates -> publish h ----
    float a_p0 = 0.f, a_p1 = 0.f;
#pragma unroll
    for (int it = 0; it < 8; ++it){
      const int k0 = it * 64 + lane * 4;
      float4 p0v = *(const float4*)(sh_p0 + k0);
      float4 p1v = *(const float4*)(sh_p1 + k0);
      fma4(a_p0, Rawhh[it], p0v);
      fma4(a_p1, Rawhh[it], p1v);
    }
    a_p0 = red16(a_p0); a_p1 = red16(a_p1);

    const float gi = sigm(a_i + b_i);
    const float go = sigm(a_o + b_o);
    const float gg = tanhf(a_g + b_g);
    float c1;
    if (t == 0){
      c1 = gi * gg;                       // c_plain with c=0
    } else {
      const float base = a_xa + ab_J;
      const float ea0 = __expf(sigm(base + a_p0));   // m0=1 for t>=1
      const float ei  = __expf(gi);
      float num = ei * gg + ea0 * sh_p0[J];
      float den = ei + ea0;
      if (t >= 3){                                    // m1=1 for t>=3
        const float ea1 = __expf(sigm(base + a_p1));
        num += ea1 * sh_p1[J];
        den += ea1;
      }
      c1 = num / den;
    }
    const float h1 = go * tanhf(c1);
    if (lane == 0){
      pub64(hpub + (size_t)par * Hq + J, h1, (unsigned)(t + 1));
      out_h[(size_t)t * Hq + J] = h1;
      out_c[(size_t)t * Hq + J] = c1;
    }

    // ---- B-pre (h NOT needed): x-word matvecs + stage x/xw(t+1) ----
    float x_f0 = 0.f, x_i0 = 0.f, x_g0 = 0.f, x_f1 = 0.f, x_i1 = 0.f, x_g1 = 0.f;
#pragma unroll
    for (int it = 0; it < 2; ++it){
      const int k0 = it * 64 + lane * 4;
      float4 x0 = *(const float4*)(shxw0[par] + k0);
      float4 x1 = *(const float4*)(shxw1[par] + k0);
      fma4(x_f0, Rwwi_f[it], x0);  fma4(x_f1, Rwwi_f[it], x1);
      fma4(x_i0, Rwwi_i[it], x0);  fma4(x_i1, Rwwi_i[it], x1);
      fma4(x_g0, Rwwi_g[it], x0);  fma4(x_g1, Rwwi_g[it], x1);
    }
    x_f0 = red16(x_f0); x_i0 = red16(x_i0); x_g0 = red16(x_g0);
    x_f1 = red16(x_f1); x_i1 = red16(x_i1); x_g1 = red16(x_g1);
    {
      const int tn = (t + 1 < Tq) ? t + 1 : t;
      if (tid < DCq){
        shx[par ^ 1][tid] = char_emb[((size_t)seq * Tq + tn) * DCq + tid];
      } else {
        const int k = tid - DCq;
        const int w0 = word_ids[((size_t)seq * Tq + tn) * 2 + 0];
        const int w1 = word_ids[((size_t)seq * Tq + tn) * 2 + 1];
        shxw0[par ^ 1][k] = sense_table[(size_t)w0 * DCq + k];
        shxw1[par ^ 1][k] = sense_table[(size_t)w1 * DCq + k];
      }
    }

    // ---- B2: poll full h(t) — THE exposed trip (volatile fast, atomic fallback)
    {
      const u64* hp = hpub + (size_t)par * Hq;
      const unsigned tg = (unsigned)(t + 1);
      u64 a = vld64(hp + i0), b = vld64(hp + i1);
      int itc = 0;
      while (!(genof(a) >= tg && genof(b) >= tg)){
        if ((++itc & 7) == 0){
          a = ld64(hp + i0);  b = ld64(hp + i1);
        } else {
          a = vld64(hp + i0); b = vld64(hp + i1);
        }
      }
      shH[par][i0] = valof(a); shH[par][i1] = valof(b);
    }
    __syncthreads();   // S2

    // ---- B3: word h-matvecs + gates -> publish pend ----
    float r_f = 0.f, r_i = 0.f, r_g = 0.f;
#pragma unroll
    for (int it = 0; it < 8; ++it){
      const int k0 = it * 64 + lane * 4;
      float4 hv = *(const float4*)(shH[par] + k0);
      fma4(r_f, Rwwh_f[it], hv);
      fma4(r_i, Rwwh_i[it], hv);
      fma4(r_g, Rwwh_g[it], hv);
    }
    r_f = red16(r_f); r_i = red16(r_i); r_g = red16(r_g);

    if (lane == 0){
      const float f0  = sigm(r_f + x_f0 + wb_f);
      const float iw0 = sigm(r_i + x_i0 + wb_i);
      const float g0  = tanhf(r_g + x_g0 + wb_g);
      const float cw0 = f0 * c1 + iw0 * g0;
      const float f1  = sigm(r_f + x_f1 + wb_f);
      const float iw1 = sigm(r_i + x_i1 + wb_i);
      const float g1  = tanhf(r_g + x_g1 + wb_g);
      const float cw1 = f1 * c1 + iw1 * g1;
      // gen = production step + 1; consumers poll p0>=t_c, p1>=t_c-2
      pub64(pnd + ((size_t)((t + 1) & 3) * 2 + 0) * Hq + J, cw0, (unsigned)(t + 1));
      pub64(pnd + ((size_t)((t + 3) & 3) * 2 + 1) * Hq + J, cw1, (unsigned)(t + 1));
    }
    // no barrier: next A1 touches only shH[par^1]/shx[par^1] (disjoint);
    // sh_p0/sh_p1 rewrites are fenced by next S1; shxw[par] reads done pre-S2.
  }
}

extern "C" void kernel_launch(void* const* d_in, const int* in_sizes, int n_in,
                              void* d_out, int out_size, void* d_ws, size_t ws_size,
                              hipStream_t stream){
  const float* char_emb = (const float*)d_in[0];
  const int*   word_ids = (const int*)d_in[1];
  const float* sense    = (const float*)d_in[2];
  const float* w_ih     = (const float*)d_in[3];
  const float* w_hh     = (const float*)d_in[4];
  const float* bb       = (const float*)d_in[5];
  const float* aw_ih    = (const float*)d_in[6];
  const float* aw_hh    = (const float*)d_in[7];
  const float* ab       = (const float*)d_in[8];
  const float* ww_ih    = (const float*)d_in[9];
  const float* ww_hh    = (const float*)d_in[10];
  const float* wb       = (const float*)d_in[11];
  unsigned char* ws = (unsigned char*)d_ws;
  float* out = (float*)d_out;

  // zero all generation words (h_pub + pend) — ws is re-poisoned before every launch
  hipMemsetAsync(ws, 0, WIHT_OFF, stream);

  // one-time (per launch) weight convert+transpose to bf16
  transpose_bf16<<<512, NTHR, 0, stream>>>(w_ih,  (__hip_bfloat16*)(ws + WIHT_OFF),  7, 128*1536, 1536);
  transpose_bf16<<<512, NTHR, 0, stream>>>(w_hh,  (__hip_bfloat16*)(ws + WHHT_OFF),  9, 512*1536, 1536);
  transpose_bf16<<<512, NTHR, 0, stream>>>(aw_ih, (__hip_bfloat16*)(ws + AWIHT_OFF), 7, 128*512,  512);
  transpose_bf16<<<512, NTHR, 0, stream>>>(aw_hh, (__hip_bfloat16*)(ws + AWHHT_OFF), 9, 512*512,  512);
  transpose_bf16<<<512, NTHR, 0, stream>>>(ww_ih, (__hip_bfloat16*)(ws + WWIHT_OFF), 7, 128*1536, 1536);
  transpose_bf16<<<512, NTHR, 0, stream>>>(ww_hh, (__hip_bfloat16*)(ws + WWHHT_OFF), 9, 512*1536, 1536);

  dim3 grid(Bq, NWG);   // x = seq (XCD-local heuristic), y = wg slice
  lattice_main<<<grid, NTHR, 0, stream>>>(char_emb, word_ids, sense, bb, ab, wb, ws, out);
}

// Round 7
// 5840.530 us; speedup vs baseline: 1.3384x; 1.3384x over previous
//
#include <hip/hip_runtime.h>
#include <hip/hip_bf16.h>

// LatticeLSTM on MI355X — Round 7: R5 single-path publication + R6 scheduling.
//  - Cross-WG datum = ONE 8B word {fp32 val, u32 gen}, published with a single
//    relaxed agent-scope atomic store (R6's dual volatile+atomic publish
//    regressed: WRITE_SIZE +75%, store-store line dependencies on the
//    critical path). Consumers poll with relaxed agent-scope atomic loads,
//    all of a thread's words issued independently per iteration.
//  - Pend loads for step t issued BEFORE A1 (latency hides under compute).
//  - h-independent reductions pre-S1; x-dependent word matvecs + reductions
//    pre-h-poll: post-S2 tail = 3 h-matvecs + 3 red16 + gates.
// pmask is data-independent: m0=(t>=1), m1=(t>=3); c_plain only at t=0.
// Progress needs all 256 WGs co-resident (1 WG/CU; LDS ~11KB, VGPR<256).

#define Bq 8
#define Tq 1024
#define DCq 128
#define Hq 512
#define NWG 32
#define NTHR 256

typedef unsigned long long u64;

// ws byte offsets
#define HPUB_OFF  0u         // u64 h_pub[8][2][512]     = 65536
#define PENDP_OFF 65536u     // u64 pend[8][4][2][512]   = 262144
#define WIHT_OFF  327680u    // bf16 [1536][128]
#define WHHT_OFF  720896u    // bf16 [1536][512]
#define AWIHT_OFF 2293760u   // bf16 [512][128]
#define AWHHT_OFF 2424832u   // bf16 [512][512]
#define WWIHT_OFF 2949120u   // bf16 [1536][128]
#define WWHHT_OFF 3342336u   // bf16 [1536][512]  (end 4915200)

__device__ __forceinline__ float bflo(unsigned u){ return __uint_as_float(u << 16); }
__device__ __forceinline__ float bfhi(unsigned u){ return __uint_as_float(u & 0xffff0000u); }
__device__ __forceinline__ float sigm(float x){ return 1.0f / (1.0f + __expf(-x)); }

__device__ __forceinline__ void fma4(float& acc, uint2 w, float4 v){
  acc = fmaf(bflo(w.x), v.x, acc);
  acc = fmaf(bfhi(w.x), v.y, acc);
  acc = fmaf(bflo(w.y), v.z, acc);
  acc = fmaf(bfhi(w.y), v.w, acc);
}

__device__ __forceinline__ float red16(float x){
  x += __shfl_xor(x, 8, 16);
  x += __shfl_xor(x, 4, 16);
  x += __shfl_xor(x, 2, 16);
  x += __shfl_xor(x, 1, 16);
  return x;
}

__device__ __forceinline__ u64 pack64(float v, unsigned gen){
  return ((u64)gen << 32) | (u64)__float_as_uint(v);
}
__device__ __forceinline__ void pub64(u64* p, float v, unsigned gen){
  __hip_atomic_store(p, pack64(v, gen), __ATOMIC_RELAXED, __HIP_MEMORY_SCOPE_AGENT);
}
__device__ __forceinline__ u64 ld64(const u64* p){
  return __hip_atomic_load(p, __ATOMIC_RELAXED, __HIP_MEMORY_SCOPE_AGENT);
}
__device__ __forceinline__ unsigned genof(u64 v){ return (unsigned)(v >> 32); }
__device__ __forceinline__ float valof(u64 v){ return __uint_as_float((unsigned)v); }

// src [K][N] fp32 -> dst [N][K] bf16 (transpose + convert). K is pow2.
__global__ void transpose_bf16(const float* __restrict__ src, __hip_bfloat16* __restrict__ dst,
                               int kshift, int total, int N){
  const int K = 1 << kshift;
  for (int idx = blockIdx.x * blockDim.x + threadIdx.x; idx < total;
       idx += gridDim.x * blockDim.x){
    int n = idx >> kshift;
    int k = idx & (K - 1);
    dst[idx] = __float2bfloat16(src[(size_t)k * N + n]);
  }
}

__global__ void __launch_bounds__(NTHR, 1)
lattice_main(const float* __restrict__ char_emb,
             const int*   __restrict__ word_ids,
             const float* __restrict__ sense_table,
             const float* __restrict__ bias_b,
             const float* __restrict__ bias_ab,
             const float* __restrict__ bias_wb,
             unsigned char* __restrict__ ws,
             float* __restrict__ out)
{
  const int seq  = blockIdx.x;
  const int wg   = blockIdx.y;
  const int tid  = threadIdx.x;
  const int grp  = tid >> 4;
  const int lane = tid & 15;
  const int J    = wg * 16 + grp;               // owned H column
  const int i0   = tid * 2, i1 = tid * 2 + 1;   // poll columns for this thread

  u64* hpub = (u64*)(ws + HPUB_OFF)  + (size_t)seq * 2 * Hq;      // [parity][col]
  u64* pnd  = (u64*)(ws + PENDP_OFF) + (size_t)seq * 4 * 2 * Hq;  // [slot][k][col]

  const uint2* w_ihT  = (const uint2*)(ws + WIHT_OFF);
  const uint2* w_hhT  = (const uint2*)(ws + WHHT_OFF);
  const uint2* aw_ihT = (const uint2*)(ws + AWIHT_OFF);
  const uint2* aw_hhT = (const uint2*)(ws + AWHHT_OFF);
  const uint2* ww_ihT = (const uint2*)(ws + WWIHT_OFF);
  const uint2* ww_hhT = (const uint2*)(ws + WWHHT_OFF);

  // ---- hoist ALL weights into registers (addresses are t-invariant) ----
  uint2 Rwhh_i[8], Rwhh_o[8], Rwhh_g[8], Rawhh[8];
  uint2 Rwwh_f[8], Rwwh_i[8], Rwwh_g[8];
  uint2 Rwih_i[2], Rwih_o[2], Rwih_g[2], Rawih[2];
  uint2 Rwwi_f[2], Rwwi_i[2], Rwwi_g[2];
  {
    const uint2* whh_i = w_hhT  + (size_t)(0*Hq + J) * 128;
    const uint2* whh_o = w_hhT  + (size_t)(1*Hq + J) * 128;
    const uint2* whh_g = w_hhT  + (size_t)(2*Hq + J) * 128;
    const uint2* awhh  = aw_hhT + (size_t)J * 128;
    const uint2* wwh_f = ww_hhT + (size_t)(0*Hq + J) * 128;
    const uint2* wwh_i = ww_hhT + (size_t)(1*Hq + J) * 128;
    const uint2* wwh_g = ww_hhT + (size_t)(2*Hq + J) * 128;
#pragma unroll
    for (int it = 0; it < 8; ++it){
      const int q = it * 16 + lane;
      Rwhh_i[it] = whh_i[q];  Rwhh_o[it] = whh_o[q];  Rwhh_g[it] = whh_g[q];
      Rawhh[it]  = awhh[q];
      Rwwh_f[it] = wwh_f[q];  Rwwh_i[it] = wwh_i[q];  Rwwh_g[it] = wwh_g[q];
    }
    const uint2* wih_i = w_ihT  + (size_t)(0*Hq + J) * 32;
    const uint2* wih_o = w_ihT  + (size_t)(1*Hq + J) * 32;
    const uint2* wih_g = w_ihT  + (size_t)(2*Hq + J) * 32;
    const uint2* awih  = aw_ihT + (size_t)J * 32;
    const uint2* wwi_f = ww_ihT + (size_t)(0*Hq + J) * 32;
    const uint2* wwi_i = ww_ihT + (size_t)(1*Hq + J) * 32;
    const uint2* wwi_g = ww_ihT + (size_t)(2*Hq + J) * 32;
#pragma unroll
    for (int it = 0; it < 2; ++it){
      const int q = it * 16 + lane;
      Rwih_i[it] = wih_i[q];  Rwih_o[it] = wih_o[q];  Rwih_g[it] = wih_g[q];
      Rawih[it]  = awih[q];
      Rwwi_f[it] = wwi_f[q];  Rwwi_i[it] = wwi_i[q];  Rwwi_g[it] = wwi_g[q];
    }
  }

  const float b_i  = bias_b[J], b_o = bias_b[Hq + J], b_g = bias_b[2*Hq + J];
  const float ab_J = bias_ab[J];
  const float wb_f = bias_wb[J], wb_i = bias_wb[Hq + J], wb_g = bias_wb[2*Hq + J];

  float* out_h = out + (size_t)seq * Tq * Hq;            // hs block
  float* out_c = out + ((size_t)Bq + seq) * Tq * Hq;     // cs block

  __shared__ __align__(16) float shH[2][Hq];      // h by parity: shH[t&1] = h(t)
  __shared__ __align__(16) float sh_p0[Hq];
  __shared__ __align__(16) float sh_p1[Hq];
  __shared__ __align__(16) float shx[2][DCq];     // x(t) in shx[t&1]
  __shared__ __align__(16) float shxw0[2][DCq];   // xw(t) in shxw*[t&1]
  __shared__ __align__(16) float shxw1[2][DCq];

  // ---- pre-loop staging: zeros + x(0), xw(0) ----
  shH[0][i0] = 0.f; shH[0][i1] = 0.f;
  shH[1][i0] = 0.f; shH[1][i1] = 0.f;
  sh_p0[i0] = 0.f; sh_p0[i1] = 0.f;
  sh_p1[i0] = 0.f; sh_p1[i1] = 0.f;
  if (tid < DCq){
    shx[0][tid] = char_emb[((size_t)seq * Tq + 0) * DCq + tid];
  } else {
    const int k = tid - DCq;
    const int w0 = word_ids[(size_t)seq * Tq * 2 + 0];
    const int w1 = word_ids[(size_t)seq * Tq * 2 + 1];
    shxw0[0][k] = sense_table[(size_t)w0 * DCq + k];
    shxw1[0][k] = sense_table[(size_t)w1 * DCq + k];
  }
  __syncthreads();

  for (int t = 0; t < Tq; ++t){
    const int par = t & 1;
    const float* hprev = shH[par ^ 1];     // h(t-1)

    // ---- pend PREFETCH (issued before A1; latency hides under compute) ----
    const u64* p0 = pnd + ((size_t)(t & 3) * 2 + 0) * Hq;
    const u64* p1 = pnd + ((size_t)(t & 3) * 2 + 1) * Hq;
    u64 qa = 0, qb = 0, qc = 0, qd = 0;
    if (t >= 1){ qa = ld64(p0 + i0); qb = ld64(p0 + i1); }
    if (t >= 3){ qc = ld64(p1 + i0); qd = ld64(p1 + i1); }

    // ---- A1: i/o/g/xa matvecs (pend NOT needed) ----
    float a_i = 0.f, a_o = 0.f, a_g = 0.f, a_xa = 0.f;
#pragma unroll
    for (int it = 0; it < 8; ++it){
      const int k0 = it * 64 + lane * 4;
      float4 hv = *(const float4*)(hprev + k0);
      fma4(a_i, Rwhh_i[it], hv);
      fma4(a_o, Rwhh_o[it], hv);
      fma4(a_g, Rwhh_g[it], hv);
    }
#pragma unroll
    for (int it = 0; it < 2; ++it){
      const int k0 = it * 64 + lane * 4;
      float4 xv = *(const float4*)(shx[par] + k0);
      fma4(a_i,  Rwih_i[it], xv);
      fma4(a_o,  Rwih_o[it], xv);
      fma4(a_g,  Rwih_g[it], xv);
      fma4(a_xa, Rawih[it],  xv);
    }
    // h-independent reductions BEFORE S1 (execute under any poll wait)
    a_i  = red16(a_i);  a_o  = red16(a_o);  a_g  = red16(a_g);  a_xa = red16(a_xa);

    // ---- A2: check prefetched pend; re-poll on miss ----
    if (t >= 3){
      const unsigned tg0 = (unsigned)t, tg1 = (unsigned)(t - 2);
      while (!(genof(qa) >= tg0 && genof(qb) >= tg0 &&
               genof(qc) >= tg1 && genof(qd) >= tg1)){
        qa = ld64(p0 + i0); qb = ld64(p0 + i1);
        qc = ld64(p1 + i0); qd = ld64(p1 + i1);
      }
      sh_p0[i0] = valof(qa); sh_p0[i1] = valof(qb);
      sh_p1[i0] = valof(qc); sh_p1[i1] = valof(qd);
    } else if (t >= 1){
      const unsigned tg0 = (unsigned)t;
      while (!(genof(qa) >= tg0 && genof(qb) >= tg0)){
        qa = ld64(p0 + i0); qb = ld64(p0 + i1);
      }
      sh_p0[i0] = valof(qa); sh_p0[i1] = valof(qb);
      // sh_p1 stays zero (m1=0 for t<3)
    }
    __syncthreads();   // S1

    // ---- A3: alpha matvecs + gates -> publish h ----
    float a_p0 = 0.f, a_p1 = 0.f;
#pragma unroll
    for (int it = 0; it < 8; ++it){
      const int k0 = it * 64 + lane * 4;
      float4 p0v = *(const float4*)(sh_p0 + k0);
      float4 p1v = *(const float4*)(sh_p1 + k0);
      fma4(a_p0, Rawhh[it], p0v);
      fma4(a_p1, Rawhh[it], p1v);
    }
    a_p0 = red16(a_p0); a_p1 = red16(a_p1);

    const float gi = sigm(a_i + b_i);
    const float go = sigm(a_o + b_o);
    const float gg = tanhf(a_g + b_g);
    float c1;
    if (t == 0){
      c1 = gi * gg;                       // c_plain with c=0
    } else {
      const float base = a_xa + ab_J;
      const float ea0 = __expf(sigm(base + a_p0));   // m0=1 for t>=1
      const float ei  = __expf(gi);
      float num = ei * gg + ea0 * sh_p0[J];
      float den = ei + ea0;
      if (t >= 3){                                    // m1=1 for t>=3
        const float ea1 = __expf(sigm(base + a_p1));
        num += ea1 * sh_p1[J];
        den += ea1;
      }
      c1 = num / den;
    }
    const float h1 = go * tanhf(c1);
    if (lane == 0){
      pub64(hpub + (size_t)par * Hq + J, h1, (unsigned)(t + 1));
      out_h[(size_t)t * Hq + J] = h1;
      out_c[(size_t)t * Hq + J] = c1;
    }

    // ---- B-pre (h NOT needed): x-word matvecs + stage x/xw(t+1) ----
    float x_f0 = 0.f, x_i0 = 0.f, x_g0 = 0.f, x_f1 = 0.f, x_i1 = 0.f, x_g1 = 0.f;
#pragma unroll
    for (int it = 0; it < 2; ++it){
      const int k0 = it * 64 + lane * 4;
      float4 x0 = *(const float4*)(shxw0[par] + k0);
      float4 x1 = *(const float4*)(shxw1[par] + k0);
      fma4(x_f0, Rwwi_f[it], x0);  fma4(x_f1, Rwwi_f[it], x1);
      fma4(x_i0, Rwwi_i[it], x0);  fma4(x_i1, Rwwi_i[it], x1);
      fma4(x_g0, Rwwi_g[it], x0);  fma4(x_g1, Rwwi_g[it], x1);
    }
    x_f0 = red16(x_f0); x_i0 = red16(x_i0); x_g0 = red16(x_g0);
    x_f1 = red16(x_f1); x_i1 = red16(x_i1); x_g1 = red16(x_g1);
    {
      const int tn = (t + 1 < Tq) ? t + 1 : t;
      if (tid < DCq){
        shx[par ^ 1][tid] = char_emb[((size_t)seq * Tq + tn) * DCq + tid];
      } else {
        const int k = tid - DCq;
        const int w0 = word_ids[((size_t)seq * Tq + tn) * 2 + 0];
        const int w1 = word_ids[((size_t)seq * Tq + tn) * 2 + 1];
        shxw0[par ^ 1][k] = sense_table[(size_t)w0 * DCq + k];
        shxw1[par ^ 1][k] = sense_table[(size_t)w1 * DCq + k];
      }
    }

    // ---- B2: poll full h(t) — THE exposed trip ----
    {
      const u64* hp = hpub + (size_t)par * Hq;
      const unsigned tg = (unsigned)(t + 1);
      u64 a = ld64(hp + i0), b = ld64(hp + i1);
      while (!(genof(a) >= tg && genof(b) >= tg)){
        a = ld64(hp + i0); b = ld64(hp + i1);
      }
      shH[par][i0] = valof(a); shH[par][i1] = valof(b);
    }
    __syncthreads();   // S2

    // ---- B3: word h-matvecs + gates -> publish pend ----
    float r_f = 0.f, r_i = 0.f, r_g = 0.f;
#pragma unroll
    for (int it = 0; it < 8; ++it){
      const int k0 = it * 64 + lane * 4;
      float4 hv = *(const float4*)(shH[par] + k0);
      fma4(r_f, Rwwh_f[it], hv);
      fma4(r_i, Rwwh_i[it], hv);
      fma4(r_g, Rwwh_g[it], hv);
    }
    r_f = red16(r_f); r_i = red16(r_i); r_g = red16(r_g);

    if (lane == 0){
      const float f0  = sigm(r_f + x_f0 + wb_f);
      const float iw0 = sigm(r_i + x_i0 + wb_i);
      const float g0  = tanhf(r_g + x_g0 + wb_g);
      const float cw0 = f0 * c1 + iw0 * g0;
      const float f1  = sigm(r_f + x_f1 + wb_f);
      const float iw1 = sigm(r_i + x_i1 + wb_i);
      const float g1  = tanhf(r_g + x_g1 + wb_g);
      const float cw1 = f1 * c1 + iw1 * g1;
      // gen = production step + 1; consumers poll p0>=t_c, p1>=t_c-2
      pub64(pnd + ((size_t)((t + 1) & 3) * 2 + 0) * Hq + J, cw0, (unsigned)(t + 1));
      pub64(pnd + ((size_t)((t + 3) & 3) * 2 + 1) * Hq + J, cw1, (unsigned)(t + 1));
    }
    // no barrier: next A1 touches only shH[par^1]/shx[par^1] (disjoint);
    // sh_p0/sh_p1 rewrites are fenced by next S1; shxw[par] reads done pre-S2.
  }
}

extern "C" void kernel_launch(void* const* d_in, const int* in_sizes, int n_in,
                              void* d_out, int out_size, void* d_ws, size_t ws_size,
                              hipStream_t stream){
  const float* char_emb = (const float*)d_in[0];
  const int*   word_ids = (const int*)d_in[1];
  const float* sense    = (const float*)d_in[2];
  const float* w_ih     = (const float*)d_in[3];
  const float* w_hh     = (const float*)d_in[4];
  const float* bb       = (const float*)d_in[5];
  const float* aw_ih    = (const float*)d_in[6];
  const float* aw_hh    = (const float*)d_in[7];
  const float* ab       = (const float*)d_in[8];
  const float* ww_ih    = (const float*)d_in[9];
  const float* ww_hh    = (const float*)d_in[10];
  const float* wb       = (const float*)d_in[11];
  unsigned char* ws = (unsigned char*)d_ws;
  float* out = (float*)d_out;

  // zero all generation words (h_pub + pend) — ws is re-poisoned before every launch
  hipMemsetAsync(ws, 0, WIHT_OFF, stream);

  // one-time (per launch) weight convert+transpose to bf16
  transpose_bf16<<<512, NTHR, 0, stream>>>(w_ih,  (__hip_bfloat16*)(ws + WIHT_OFF),  7, 128*1536, 1536);
  transpose_bf16<<<512, NTHR, 0, stream>>>(w_hh,  (__hip_bfloat16*)(ws + WHHT_OFF),  9, 512*1536, 1536);
  transpose_bf16<<<512, NTHR, 0, stream>>>(aw_ih, (__hip_bfloat16*)(ws + AWIHT_OFF), 7, 128*512,  512);
  transpose_bf16<<<512, NTHR, 0, stream>>>(aw_hh, (__hip_bfloat16*)(ws + AWHHT_OFF), 9, 512*512,  512);
  transpose_bf16<<<512, NTHR, 0, stream>>>(ww_ih, (__hip_bfloat16*)(ws + WWIHT_OFF), 7, 128*1536, 1536);
  transpose_bf16<<<512, NTHR, 0, stream>>>(ww_hh, (__hip_bfloat16*)(ws + WWHHT_OFF), 9, 512*1536, 1536);

  dim3 grid(Bq, NWG);   // x = seq (XCD-local heuristic), y = wg slice
  lattice_main<<<grid, NTHR, 0, stream>>>(char_emb, word_ids, sense, bb, ab, wb, ws, out);
}

// Round 8
// 5816.687 us; speedup vs baseline: 1.3439x; 1.0041x over previous
//
#include <hip/hip_runtime.h>
#include <hip/hip_bf16.h>

// LatticeLSTM on MI355X — Round 8: packed h-broadcast (2 bf16 cols + gen / u64).
//  - h publication: u64 word w = {lo16: bf16 h[2w], mid16: bf16 h[2w+1],
//    hi32: gen}. 256 words instead of 512 -> half the poll requests (1 word
//    per thread) and half the publish stores (8 per WG, paired across
//    adjacent groups via __shfl_xor(h1,16); post-red16 all lanes hold h1).
//    MALL burst per h-trip is message-count bound (R7 post-mortem: 16K
//    requests/iter) -> halving messages should cut the exposed trip.
//  - pend stays fp32/u64-per-col (feeds the VALUE path in c_lat; h only feeds
//    bf16-weighted matvecs, so bf16 h adds error ~ existing weight error).
//  - Everything else per R7: single relaxed agent-scope atomic publish/poll,
//    pend prefetch before A1, h-independent reductions pre-S1, x-word matvecs
//    pre-h-poll, 2 syncthreads/step.
// pmask is data-independent: m0=(t>=1), m1=(t>=3); c_plain only at t=0.
// Progress needs all 256 WGs co-resident (1 WG/CU; LDS ~11KB, VGPR<256).

#define Bq 8
#define Tq 1024
#define DCq 128
#define Hq 512
#define NWG 32
#define NTHR 256

typedef unsigned long long u64;

// ws byte offsets
#define HPUB_OFF  0u         // u64 h_pub[8][2][256]     = 32768 (gap to 65536)
#define PENDP_OFF 65536u     // u64 pend[8][4][2][512]   = 262144
#define WIHT_OFF  327680u    // bf16 [1536][128]
#define WHHT_OFF  720896u    // bf16 [1536][512]
#define AWIHT_OFF 2293760u   // bf16 [512][128]
#define AWHHT_OFF 2424832u   // bf16 [512][512]
#define WWIHT_OFF 2949120u   // bf16 [1536][128]
#define WWHHT_OFF 3342336u   // bf16 [1536][512]  (end 4915200)

__device__ __forceinline__ float bflo(unsigned u){ return __uint_as_float(u << 16); }
__device__ __forceinline__ float bfhi(unsigned u){ return __uint_as_float(u & 0xffff0000u); }
__device__ __forceinline__ float sigm(float x){ return 1.0f / (1.0f + __expf(-x)); }

// fp32 -> bf16 bits (RNE)
__device__ __forceinline__ unsigned f2bf(float f){
  unsigned u = __float_as_uint(f);
  u += 0x7fffu + ((u >> 16) & 1u);
  return u >> 16;
}

__device__ __forceinline__ void fma4(float& acc, uint2 w, float4 v){
  acc = fmaf(bflo(w.x), v.x, acc);
  acc = fmaf(bfhi(w.x), v.y, acc);
  acc = fmaf(bflo(w.y), v.z, acc);
  acc = fmaf(bfhi(w.y), v.w, acc);
}

__device__ __forceinline__ float red16(float x){
  x += __shfl_xor(x, 8, 16);
  x += __shfl_xor(x, 4, 16);
  x += __shfl_xor(x, 2, 16);
  x += __shfl_xor(x, 1, 16);
  return x;
}

__device__ __forceinline__ u64 pack64(float v, unsigned gen){
  return ((u64)gen << 32) | (u64)__float_as_uint(v);
}
__device__ __forceinline__ void st64(u64* p, u64 w){
  __hip_atomic_store(p, w, __ATOMIC_RELAXED, __HIP_MEMORY_SCOPE_AGENT);
}
__device__ __forceinline__ void pub64(u64* p, float v, unsigned gen){
  st64(p, pack64(v, gen));
}
__device__ __forceinline__ u64 ld64(const u64* p){
  return __hip_atomic_load(p, __ATOMIC_RELAXED, __HIP_MEMORY_SCOPE_AGENT);
}
__device__ __forceinline__ unsigned genof(u64 v){ return (unsigned)(v >> 32); }
__device__ __forceinline__ float valof(u64 v){ return __uint_as_float((unsigned)v); }

// src [K][N] fp32 -> dst [N][K] bf16 (transpose + convert). K is pow2.
__global__ void transpose_bf16(const float* __restrict__ src, __hip_bfloat16* __restrict__ dst,
                               int kshift, int total, int N){
  const int K = 1 << kshift;
  for (int idx = blockIdx.x * blockDim.x + threadIdx.x; idx < total;
       idx += gridDim.x * blockDim.x){
    int n = idx >> kshift;
    int k = idx & (K - 1);
    dst[idx] = __float2bfloat16(src[(size_t)k * N + n]);
  }
}

__global__ void __launch_bounds__(NTHR, 1)
lattice_main(const float* __restrict__ char_emb,
             const int*   __restrict__ word_ids,
             const float* __restrict__ sense_table,
             const float* __restrict__ bias_b,
             const float* __restrict__ bias_ab,
             const float* __restrict__ bias_wb,
             unsigned char* __restrict__ ws,
             float* __restrict__ out)
{
  const int seq  = blockIdx.x;
  const int wg   = blockIdx.y;
  const int tid  = threadIdx.x;
  const int grp  = tid >> 4;
  const int lane = tid & 15;
  const int J    = wg * 16 + grp;               // owned H column
  const int i0   = tid * 2, i1 = tid * 2 + 1;   // poll columns for this thread

  u64* hpub = (u64*)(ws + HPUB_OFF)  + (size_t)seq * 2 * 256;     // [parity][word]
  u64* pnd  = (u64*)(ws + PENDP_OFF) + (size_t)seq * 4 * 2 * Hq;  // [slot][k][col]

  const uint2* w_ihT  = (const uint2*)(ws + WIHT_OFF);
  const uint2* w_hhT  = (const uint2*)(ws + WHHT_OFF);
  const uint2* aw_ihT = (const uint2*)(ws + AWIHT_OFF);
  const uint2* aw_hhT = (const uint2*)(ws + AWHHT_OFF);
  const uint2* ww_ihT = (const uint2*)(ws + WWIHT_OFF);
  const uint2* ww_hhT = (const uint2*)(ws + WWHHT_OFF);

  // ---- hoist ALL weights into registers (addresses are t-invariant) ----
  uint2 Rwhh_i[8], Rwhh_o[8], Rwhh_g[8], Rawhh[8];
  uint2 Rwwh_f[8], Rwwh_i[8], Rwwh_g[8];
  uint2 Rwih_i[2], Rwih_o[2], Rwih_g[2], Rawih[2];
  uint2 Rwwi_f[2], Rwwi_i[2], Rwwi_g[2];
  {
    const uint2* whh_i = w_hhT  + (size_t)(0*Hq + J) * 128;
    const uint2* whh_o = w_hhT  + (size_t)(1*Hq + J) * 128;
    const uint2* whh_g = w_hhT  + (size_t)(2*Hq + J) * 128;
    const uint2* awhh  = aw_hhT + (size_t)J * 128;
    const uint2* wwh_f = ww_hhT + (size_t)(0*Hq + J) * 128;
    const uint2* wwh_i = ww_hhT + (size_t)(1*Hq + J) * 128;
    const uint2* wwh_g = ww_hhT + (size_t)(2*Hq + J) * 128;
#pragma unroll
    for (int it = 0; it < 8; ++it){
      const int q = it * 16 + lane;
      Rwhh_i[it] = whh_i[q];  Rwhh_o[it] = whh_o[q];  Rwhh_g[it] = whh_g[q];
      Rawhh[it]  = awhh[q];
      Rwwh_f[it] = wwh_f[q];  Rwwh_i[it] = wwh_i[q];  Rwwh_g[it] = wwh_g[q];
    }
    const uint2* wih_i = w_ihT  + (size_t)(0*Hq + J) * 32;
    const uint2* wih_o = w_ihT  + (size_t)(1*Hq + J) * 32;
    const uint2* wih_g = w_ihT  + (size_t)(2*Hq + J) * 32;
    const uint2* awih  = aw_ihT + (size_t)J * 32;
    const uint2* wwi_f = ww_ihT + (size_t)(0*Hq + J) * 32;
    const uint2* wwi_i = ww_ihT + (size_t)(1*Hq + J) * 32;
    const uint2* wwi_g = ww_ihT + (size_t)(2*Hq + J) * 32;
#pragma unroll
    for (int it = 0; it < 2; ++it){
      const int q = it * 16 + lane;
      Rwih_i[it] = wih_i[q];  Rwih_o[it] = wih_o[q];  Rwih_g[it] = wih_g[q];
      Rawih[it]  = awih[q];
      Rwwi_f[it] = wwi_f[q];  Rwwi_i[it] = wwi_i[q];  Rwwi_g[it] = wwi_g[q];
    }
  }

  const float b_i  = bias_b[J], b_o = bias_b[Hq + J], b_g = bias_b[2*Hq + J];
  const float ab_J = bias_ab[J];
  const float wb_f = bias_wb[J], wb_i = bias_wb[Hq + J], wb_g = bias_wb[2*Hq + J];

  float* out_h = out + (size_t)seq * Tq * Hq;            // hs block
  float* out_c = out + ((size_t)Bq + seq) * Tq * Hq;     // cs block

  __shared__ __align__(16) float shH[2][Hq];      // h by parity: shH[t&1] = h(t)
  __shared__ __align__(16) float sh_p0[Hq];
  __shared__ __align__(16) float sh_p1[Hq];
  __shared__ __align__(16) float shx[2][DCq];     // x(t) in shx[t&1]
  __shared__ __align__(16) float shxw0[2][DCq];   // xw(t) in shxw*[t&1]
  __shared__ __align__(16) float shxw1[2][DCq];

  // ---- pre-loop staging: zeros + x(0), xw(0) ----
  shH[0][i0] = 0.f; shH[0][i1] = 0.f;
  shH[1][i0] = 0.f; shH[1][i1] = 0.f;
  sh_p0[i0] = 0.f; sh_p0[i1] = 0.f;
  sh_p1[i0] = 0.f; sh_p1[i1] = 0.f;
  if (tid < DCq){
    shx[0][tid] = char_emb[((size_t)seq * Tq + 0) * DCq + tid];
  } else {
    const int k = tid - DCq;
    const int w0 = word_ids[(size_t)seq * Tq * 2 + 0];
    const int w1 = word_ids[(size_t)seq * Tq * 2 + 1];
    shxw0[0][k] = sense_table[(size_t)w0 * DCq + k];
    shxw1[0][k] = sense_table[(size_t)w1 * DCq + k];
  }
  __syncthreads();

  for (int t = 0; t < Tq; ++t){
    const int par = t & 1;
    const float* hprev = shH[par ^ 1];     // h(t-1)

    // ---- pend PREFETCH (issued before A1; latency hides under compute) ----
    const u64* p0 = pnd + ((size_t)(t & 3) * 2 + 0) * Hq;
    const u64* p1 = pnd + ((size_t)(t & 3) * 2 + 1) * Hq;
    u64 qa = 0, qb = 0, qc = 0, qd = 0;
    if (t >= 1){ qa = ld64(p0 + i0); qb = ld64(p0 + i1); }
    if (t >= 3){ qc = ld64(p1 + i0); qd = ld64(p1 + i1); }

    // ---- A1: i/o/g/xa matvecs (pend NOT needed) ----
    float a_i = 0.f, a_o = 0.f, a_g = 0.f, a_xa = 0.f;
#pragma unroll
    for (int it = 0; it < 8; ++it){
      const int k0 = it * 64 + lane * 4;
      float4 hv = *(const float4*)(hprev + k0);
      fma4(a_i, Rwhh_i[it], hv);
      fma4(a_o, Rwhh_o[it], hv);
      fma4(a_g, Rwhh_g[it], hv);
    }
#pragma unroll
    for (int it = 0; it < 2; ++it){
      const int k0 = it * 64 + lane * 4;
      float4 xv = *(const float4*)(shx[par] + k0);
      fma4(a_i,  Rwih_i[it], xv);
      fma4(a_o,  Rwih_o[it], xv);
      fma4(a_g,  Rwih_g[it], xv);
      fma4(a_xa, Rawih[it],  xv);
    }
    // h-independent reductions BEFORE S1 (execute under any poll wait)
    a_i  = red16(a_i);  a_o  = red16(a_o);  a_g  = red16(a_g);  a_xa = red16(a_xa);

    // ---- A2: check prefetched pend; re-poll on miss ----
    if (t >= 3){
      const unsigned tg0 = (unsigned)t, tg1 = (unsigned)(t - 2);
      while (!(genof(qa) >= tg0 && genof(qb) >= tg0 &&
               genof(qc) >= tg1 && genof(qd) >= tg1)){
        qa = ld64(p0 + i0); qb = ld64(p0 + i1);
        qc = ld64(p1 + i0); qd = ld64(p1 + i1);
      }
      sh_p0[i0] = valof(qa); sh_p0[i1] = valof(qb);
      sh_p1[i0] = valof(qc); sh_p1[i1] = valof(qd);
    } else if (t >= 1){
      const unsigned tg0 = (unsigned)t;
      while (!(genof(qa) >= tg0 && genof(qb) >= tg0)){
        qa = ld64(p0 + i0); qb = ld64(p0 + i1);
      }
      sh_p0[i0] = valof(qa); sh_p0[i1] = valof(qb);
      // sh_p1 stays zero (m1=0 for t<3)
    }
    __syncthreads();   // S1

    // ---- A3: alpha matvecs + gates -> publish h (packed 2 cols/word) ----
    float a_p0 = 0.f, a_p1 = 0.f;
#pragma unroll
    for (int it = 0; it < 8; ++it){
      const int k0 = it * 64 + lane * 4;
      float4 p0v = *(const float4*)(sh_p0 + k0);
      float4 p1v = *(const float4*)(sh_p1 + k0);
      fma4(a_p0, Rawhh[it], p0v);
      fma4(a_p1, Rawhh[it], p1v);
    }
    a_p0 = red16(a_p0); a_p1 = red16(a_p1);

    const float gi = sigm(a_i + b_i);
    const float go = sigm(a_o + b_o);
    const float gg = tanhf(a_g + b_g);
    float c1;
    if (t == 0){
      c1 = gi * gg;                       // c_plain with c=0
    } else {
      const float base = a_xa + ab_J;
      const float ea0 = __expf(sigm(base + a_p0));   // m0=1 for t>=1
      const float ei  = __expf(gi);
      float num = ei * gg + ea0 * sh_p0[J];
      float den = ei + ea0;
      if (t >= 3){                                    // m1=1 for t>=3
        const float ea1 = __expf(sigm(base + a_p1));
        num += ea1 * sh_p1[J];
        den += ea1;
      }
      c1 = num / den;
    }
    const float h1 = go * tanhf(c1);
    // pair h1 of adjacent groups: lane l <-> l^16 (groups 2k <-> 2k+1)
    const float h1o = __shfl_xor(h1, 16);   // all lanes hold h1 post-red16
    if (lane == 0){
      if ((grp & 1) == 0){
        const u64 w = ((u64)(unsigned)(t + 1) << 32)
                    | ((u64)f2bf(h1o) << 16) | (u64)f2bf(h1);
        st64(hpub + (size_t)par * 256 + (J >> 1), w);   // word (J/2): cols J, J+1
      }
      out_h[(size_t)t * Hq + J] = h1;
      out_c[(size_t)t * Hq + J] = c1;
    }

    // ---- B-pre (h NOT needed): x-word matvecs + stage x/xw(t+1) ----
    float x_f0 = 0.f, x_i0 = 0.f, x_g0 = 0.f, x_f1 = 0.f, x_i1 = 0.f, x_g1 = 0.f;
#pragma unroll
    for (int it = 0; it < 2; ++it){
      const int k0 = it * 64 + lane * 4;
      float4 x0 = *(const float4*)(shxw0[par] + k0);
      float4 x1 = *(const float4*)(shxw1[par] + k0);
      fma4(x_f0, Rwwi_f[it], x0);  fma4(x_f1, Rwwi_f[it], x1);
      fma4(x_i0, Rwwi_i[it], x0);  fma4(x_i1, Rwwi_i[it], x1);
      fma4(x_g0, Rwwi_g[it], x0);  fma4(x_g1, Rwwi_g[it], x1);
    }
    x_f0 = red16(x_f0); x_i0 = red16(x_i0); x_g0 = red16(x_g0);
    x_f1 = red16(x_f1); x_i1 = red16(x_i1); x_g1 = red16(x_g1);
    {
      const int tn = (t + 1 < Tq) ? t + 1 : t;
      if (tid < DCq){
        shx[par ^ 1][tid] = char_emb[((size_t)seq * Tq + tn) * DCq + tid];
      } else {
        const int k = tid - DCq;
        const int w0 = word_ids[((size_t)seq * Tq + tn) * 2 + 0];
        const int w1 = word_ids[((size_t)seq * Tq + tn) * 2 + 1];
        shxw0[par ^ 1][k] = sense_table[(size_t)w0 * DCq + k];
        shxw1[par ^ 1][k] = sense_table[(size_t)w1 * DCq + k];
      }
    }

    // ---- B2: poll packed h(t) — ONE word per thread (256 req/WG/iter) ----
    {
      const u64* hp = hpub + (size_t)par * 256;
      const unsigned tg = (unsigned)(t + 1);
      u64 a = ld64(hp + tid);
      while (genof(a) < tg) a = ld64(hp + tid);
      shH[par][i0] = bflo((unsigned)a & 0xffffu);
      shH[par][i1] = bflo(((unsigned)a >> 16) & 0xffffu);
    }
    __syncthreads();   // S2

    // ---- B3: word h-matvecs + gates -> publish pend ----
    float r_f = 0.f, r_i = 0.f, r_g = 0.f;
#pragma unroll
    for (int it = 0; it < 8; ++it){
      const int k0 = it * 64 + lane * 4;
      float4 hv = *(const float4*)(shH[par] + k0);
      fma4(r_f, Rwwh_f[it], hv);
      fma4(r_i, Rwwh_i[it], hv);
      fma4(r_g, Rwwh_g[it], hv);
    }
    r_f = red16(r_f); r_i = red16(r_i); r_g = red16(r_g);

    if (lane == 0){
      const float f0  = sigm(r_f + x_f0 + wb_f);
      const float iw0 = sigm(r_i + x_i0 + wb_i);
      const float g0  = tanhf(r_g + x_g0 + wb_g);
      const float cw0 = f0 * c1 + iw0 * g0;
      const float f1  = sigm(r_f + x_f1 + wb_f);
      const float iw1 = sigm(r_i + x_i1 + wb_i);
      const float g1  = tanhf(r_g + x_g1 + wb_g);
      const float cw1 = f1 * c1 + iw1 * g1;
      // gen = production step + 1; consumers poll p0>=t_c, p1>=t_c-2
      pub64(pnd + ((size_t)((t + 1) & 3) * 2 + 0) * Hq + J, cw0, (unsigned)(t + 1));
      pub64(pnd + ((size_t)((t + 3) & 3) * 2 + 1) * Hq + J, cw1, (unsigned)(t + 1));
    }
    // no barrier: next A1 touches only shH[par^1]/shx[par^1] (disjoint);
    // sh_p0/sh_p1 rewrites are fenced by next S1; shxw[par] reads done pre-S2.
  }
}

extern "C" void kernel_launch(void* const* d_in, const int* in_sizes, int n_in,
                              void* d_out, int out_size, void* d_ws, size_t ws_size,
                              hipStream_t stream){
  const float* char_emb = (const float*)d_in[0];
  const int*   word_ids = (const int*)d_in[1];
  const float* sense    = (const float*)d_in[2];
  const float* w_ih     = (const float*)d_in[3];
  const float* w_hh     = (const float*)d_in[4];
  const float* bb       = (const float*)d_in[5];
  const float* aw_ih    = (const float*)d_in[6];
  const float* aw_hh    = (const float*)d_in[7];
  const float* ab       = (const float*)d_in[8];
  const float* ww_ih    = (const float*)d_in[9];
  const float* ww_hh    = (const float*)d_in[10];
  const float* wb       = (const float*)d_in[11];
  unsigned char* ws = (unsigned char*)d_ws;
  float* out = (float*)d_out;

  // zero all generation words (h_pub + pend) — ws is re-poisoned before every launch
  hipMemsetAsync(ws, 0, WIHT_OFF, stream);

  // one-time (per launch) weight convert+transpose to bf16
  transpose_bf16<<<512, NTHR, 0, stream>>>(w_ih,  (__hip_bfloat16*)(ws + WIHT_OFF),  7, 128*1536, 1536);
  transpose_bf16<<<512, NTHR, 0, stream>>>(w_hh,  (__hip_bfloat16*)(ws + WHHT_OFF),  9, 512*1536, 1536);
  transpose_bf16<<<512, NTHR, 0, stream>>>(aw_ih, (__hip_bfloat16*)(ws + AWIHT_OFF), 7, 128*512,  512);
  transpose_bf16<<<512, NTHR, 0, stream>>>(aw_hh, (__hip_bfloat16*)(ws + AWHHT_OFF), 9, 512*512,  512);
  transpose_bf16<<<512, NTHR, 0, stream>>>(ww_ih, (__hip_bfloat16*)(ws + WWIHT_OFF), 7, 128*1536, 1536);
  transpose_bf16<<<512, NTHR, 0, stream>>>(ww_hh, (__hip_bfloat16*)(ws + WWHHT_OFF), 9, 512*1536, 1536);

  dim3 grid(Bq, NWG);   // x = seq (XCD-local heuristic), y = wg slice
  lattice_main<<<grid, NTHR, 0, stream>>>(char_emb, word_ids, sense, bb, ab, wb, ws, out);
}